// Round 1
// baseline (2475.453 us; speedup 1.0000x reference)
//
#include <hip/hip_runtime.h>
#include <math.h>

#define B_ 32
#define T_ 2048
#define N_ 2048
#define D_ 512
#define L_ 256
#define TE_ 1024
#define H_ 8
#define HD_ 64
#define MROWS 65536  // B*T = B*N

// ---------------- block reduce (256 threads) ----------------
__device__ __forceinline__ float blockReduceSum(float v, float* ws) {
#pragma unroll
  for (int m = 32; m >= 1; m >>= 1) v += __shfl_xor(v, m, 64);
  int wid = threadIdx.x >> 6;
  int lane = threadIdx.x & 63;
  __syncthreads();  // protect ws reuse across calls
  if (lane == 0) ws[wid] = v;
  __syncthreads();
  return ws[0] + ws[1] + ws[2] + ws[3];
}

// ---------------- row LayerNorm ----------------
template <int COLS>
__global__ void __launch_bounds__(256) ln_rows(const float* __restrict__ in,
                                               const float* __restrict__ g,
                                               const float* __restrict__ bb,
                                               float* __restrict__ out) {
  constexpr int E = COLS / 256;
  __shared__ float ws[4];
  size_t row = blockIdx.x;
  const float* rp = in + row * COLS;
  float v[E];
  float s = 0.f;
#pragma unroll
  for (int e = 0; e < E; ++e) {
    v[e] = rp[threadIdx.x + e * 256];
    s += v[e];
  }
  s = blockReduceSum(s, ws);
  float mean = s * (1.0f / COLS);
  float q = 0.f;
#pragma unroll
  for (int e = 0; e < E; ++e) {
    float d = v[e] - mean;
    q += d * d;
  }
  q = blockReduceSum(q, ws);
  float rstd = rsqrtf(q * (1.0f / COLS) + 1e-5f);
  float* op = out + row * COLS;
#pragma unroll
  for (int e = 0; e < E; ++e) {
    int c = threadIdx.x + e * 256;
    op[c] = (v[e] - mean) * rstd * g[c] + bb[c];
  }
}

// ---------------- tiled fp32 GEMM: C[M,N] = A[M,KT] @ W[KT,N] + bias (+add) ----------------
template <int KT, bool ADD>
__global__ void __launch_bounds__(256) gemm64(const float* __restrict__ A,
                                              const float* __restrict__ W,
                                              const float* __restrict__ bias,
                                              const float* __restrict__ add,
                                              float* __restrict__ C, int Ncols) {
  __shared__ float As[16][68];  // [k][m]
  __shared__ float Ws[16][68];  // [k][n]
  int tid = threadIdx.x;
  int tx = tid & 15, ty = tid >> 4;
  size_t row0 = (size_t)blockIdx.y * 64;
  int col0 = blockIdx.x * 64;
  float acc[4][4] = {};
  int am = tid >> 2, ak = (tid & 3) * 4;
  int wk = tid >> 4, wn = (tid & 15) * 4;
  for (int k0 = 0; k0 < KT; k0 += 16) {
    float4 a = *(const float4*)&A[(row0 + am) * KT + k0 + ak];
    float4 w = *(const float4*)&W[(size_t)(k0 + wk) * Ncols + col0 + wn];
    __syncthreads();  // previous compute must finish before overwrite
    As[ak + 0][am] = a.x;
    As[ak + 1][am] = a.y;
    As[ak + 2][am] = a.z;
    As[ak + 3][am] = a.w;
    Ws[wk][wn + 0] = w.x;
    Ws[wk][wn + 1] = w.y;
    Ws[wk][wn + 2] = w.z;
    Ws[wk][wn + 3] = w.w;
    __syncthreads();
#pragma unroll
    for (int kk = 0; kk < 16; ++kk) {
      float av[4], wv[4];
#pragma unroll
      for (int i = 0; i < 4; ++i) av[i] = As[kk][ty * 4 + i];
#pragma unroll
      for (int j = 0; j < 4; ++j) wv[j] = Ws[kk][tx * 4 + j];
#pragma unroll
      for (int i = 0; i < 4; ++i)
#pragma unroll
        for (int j = 0; j < 4; ++j) acc[i][j] += av[i] * wv[j];
    }
  }
#pragma unroll
  for (int i = 0; i < 4; ++i) {
    size_t r = row0 + ty * 4 + i;
#pragma unroll
    for (int j = 0; j < 4; ++j) {
      int c = col0 + tx * 4 + j;
      float val = acc[i][j] + bias[c];
      if constexpr (ADD) val += add[r * (size_t)Ncols + c];
      C[r * (size_t)Ncols + c] = val;
    }
  }
}

// ---------------- softmax over contiguous 64-groups (q) ----------------
__global__ void __launch_bounds__(256) qsoftmax(float* __restrict__ q) {
  size_t w = (size_t)blockIdx.x * 4 + (threadIdx.x >> 6);
  int lane = threadIdx.x & 63;
  size_t idx = w * 64 + lane;  // row*512 + g*64 + lane, contiguous groups
  float v = q[idx];
  float m = v;
#pragma unroll
  for (int s = 32; s >= 1; s >>= 1) m = fmaxf(m, __shfl_xor(m, s, 64));
  float e = expf(v - m);
  float ssum = e;
#pragma unroll
  for (int s = 32; s >= 1; s >>= 1) ssum += __shfl_xor(ssum, s, 64);
  q[idx] = e / ssum;
}

// ---------------- k softmax stats over n (per b, channel) ----------------
__global__ void __launch_bounds__(256) kstats(const float* __restrict__ k,
                                              float* __restrict__ kmax,
                                              float* __restrict__ ksum) {
  int b = blockIdx.x, cg = blockIdx.y;
  int tid = threadIdx.x;
  int lane = tid & 63, slice = tid >> 6;
  int c = cg * 64 + lane;
  const float* kp = k + (size_t)b * N_ * D_ + c;
  float m = -1e30f;
  for (int n = slice; n < N_; n += 4) m = fmaxf(m, kp[(size_t)n * D_]);
  __shared__ float red[256];
  __shared__ float mxs[64];
  red[tid] = m;
  __syncthreads();
  if (tid < 64)
    mxs[tid] = fmaxf(fmaxf(red[tid], red[tid + 64]), fmaxf(red[tid + 128], red[tid + 192]));
  __syncthreads();
  float mm = mxs[lane];
  float s = 0.f;
  for (int n = slice; n < N_; n += 4) s += expf(kp[(size_t)n * D_] - mm);
  __syncthreads();
  red[tid] = s;
  __syncthreads();
  if (tid < 64) {
    float ss = red[tid] + red[tid + 64] + red[tid + 128] + red[tid + 192];
    kmax[b * D_ + cg * 64 + tid] = mxs[tid];
    ksum[b * D_ + cg * 64 + tid] = ss;
  }
}

// ---------------- attn[b,h] += Kx^T @ V over an n-chunk of 256 ----------------
__global__ void __launch_bounds__(256) attn_kernel(const float* __restrict__ k,
                                                   const float* __restrict__ v,
                                                   const float* __restrict__ kmax,
                                                   const float* __restrict__ ksum,
                                                   float* __restrict__ attn) {
  int b = blockIdx.x, h = blockIdx.y, nc = blockIdx.z;
  int tid = threadIdx.x;
  __shared__ float ks_[32][68];
  __shared__ float vs_[32][68];
  __shared__ float mx[64], is_[64];
  if (tid < 64) {
    mx[tid] = kmax[b * D_ + h * 64 + tid];
    is_[tid] = 1.f / ksum[b * D_ + h * 64 + tid];
  }
  const float* kp = k + ((size_t)b * N_ + nc * 256) * D_ + h * 64;
  const float* vp = v + ((size_t)b * N_ + nc * 256) * D_ + h * 64;
  float acc[4][4] = {};
  int tx = tid & 15, ty = tid >> 4;
  int lr = tid >> 4;        // 0..15
  int c4 = (tid & 15) * 4;  // 0..60
  for (int n0 = 0; n0 < 256; n0 += 32) {
    __syncthreads();
#pragma unroll
    for (int rr = 0; rr < 32; rr += 16) {
      float4 kv = *(const float4*)&kp[(size_t)(n0 + lr + rr) * D_ + c4];
      float4 vv = *(const float4*)&vp[(size_t)(n0 + lr + rr) * D_ + c4];
      ks_[lr + rr][c4 + 0] = expf(kv.x - mx[c4 + 0]) * is_[c4 + 0];
      ks_[lr + rr][c4 + 1] = expf(kv.y - mx[c4 + 1]) * is_[c4 + 1];
      ks_[lr + rr][c4 + 2] = expf(kv.z - mx[c4 + 2]) * is_[c4 + 2];
      ks_[lr + rr][c4 + 3] = expf(kv.w - mx[c4 + 3]) * is_[c4 + 3];
      vs_[lr + rr][c4 + 0] = vv.x;
      vs_[lr + rr][c4 + 1] = vv.y;
      vs_[lr + rr][c4 + 2] = vv.z;
      vs_[lr + rr][c4 + 3] = vv.w;
    }
    __syncthreads();
#pragma unroll
    for (int nn = 0; nn < 32; ++nn) {
      float av[4], bv2[4];
#pragma unroll
      for (int i = 0; i < 4; ++i) av[i] = ks_[nn][ty * 4 + i];
#pragma unroll
      for (int j = 0; j < 4; ++j) bv2[j] = vs_[nn][tx * 4 + j];
#pragma unroll
      for (int i = 0; i < 4; ++i)
#pragma unroll
        for (int j = 0; j < 4; ++j) acc[i][j] += av[i] * bv2[j];
    }
  }
  float* ap = attn + (size_t)(b * H_ + h) * 4096;
#pragma unroll
  for (int i = 0; i < 4; ++i)
#pragma unroll
    for (int j = 0; j < 4; ++j)
      atomicAdd(&ap[(ty * 4 + i) * 64 + tx * 4 + j], acc[i][j]);
}

// ---------------- emb modulation: eo = silu(emb) @ We + be ----------------
__global__ void __launch_bounds__(256) embmod(const float* __restrict__ emb,
                                              const float* __restrict__ We,
                                              const float* __restrict__ be,
                                              float* __restrict__ eo) {
  int b = blockIdx.x, tid = threadIdx.x;
  __shared__ float se[TE_];
  for (int i = tid; i < TE_; i += 256) {
    float e = emb[b * TE_ + i];
    se[i] = e / (1.f + expf(-e));
  }
  __syncthreads();
  int j0 = tid * 4;
  float a0 = 0, a1 = 0, a2 = 0, a3 = 0;
  for (int i = 0; i < TE_; ++i) {
    float s = se[i];
    float4 wv = *(const float4*)&We[(size_t)i * 1024 + j0];
    a0 += s * wv.x;
    a1 += s * wv.y;
    a2 += s * wv.z;
    a3 += s * wv.w;
  }
  eo[b * 1024 + j0 + 0] = a0 + be[j0 + 0];
  eo[b * 1024 + j0 + 1] = a1 + be[j0 + 1];
  eo[b * 1024 + j0 + 2] = a2 + be[j0 + 2];
  eo[b * 1024 + j0 + 3] = a3 + be[j0 + 3];
}

// ---------------- y[b,t,h,:] = q[b,t,h,:] @ attn[b,h] ----------------
__global__ void __launch_bounds__(256) yein(const float* __restrict__ q,
                                            const float* __restrict__ attn,
                                            float* __restrict__ y) {
  int t0 = blockIdx.x * 32, h = blockIdx.y, b = blockIdx.z;
  int tid = threadIdx.x;
  __shared__ float at[64][68];
  __shared__ float qs[32][68];
  const float* ap = attn + (size_t)(b * H_ + h) * 4096;
  for (int i = tid; i < 4096; i += 256) at[i >> 6][i & 63] = ap[i];
  const float* qp = q + ((size_t)b * T_ + t0) * D_ + h * 64;
  for (int i = tid; i < 2048; i += 256)
    qs[i >> 6][i & 63] = qp[(size_t)(i >> 6) * D_ + (i & 63)];
  __syncthreads();
  int r = tid >> 3, c0 = (tid & 7) * 8;
  float acc[8] = {};
#pragma unroll
  for (int d = 0; d < 64; ++d) {
    float qv = qs[r][d];
#pragma unroll
    for (int j = 0; j < 8; ++j) acc[j] += qv * at[d][c0 + j];
  }
  float* yp = y + ((size_t)b * T_ + t0 + r) * D_ + h * 64 + c0;
#pragma unroll
  for (int j = 0; j < 8; ++j) yp[j] = acc[j];
}

// ---------------- LN(y) * (1+scale) + shift, then silu ----------------
__global__ void __launch_bounds__(256) modln(const float* __restrict__ y,
                                             const float* __restrict__ sg,
                                             const float* __restrict__ sb,
                                             const float* __restrict__ eo,
                                             float* __restrict__ hs) {
  __shared__ float ws[4];
  size_t row = blockIdx.x;
  int b = (int)(row >> 11);  // T_ = 2048 rows per batch
  const float* rp = y + row * D_;
  float v[2];
  float s = 0.f;
#pragma unroll
  for (int e = 0; e < 2; ++e) {
    v[e] = rp[threadIdx.x + e * 256];
    s += v[e];
  }
  s = blockReduceSum(s, ws);
  float mean = s * (1.0f / D_);
  float q = 0.f;
#pragma unroll
  for (int e = 0; e < 2; ++e) {
    float d = v[e] - mean;
    q += d * d;
  }
  q = blockReduceSum(q, ws);
  float rstd = rsqrtf(q * (1.0f / D_) + 1e-5f);
#pragma unroll
  for (int e = 0; e < 2; ++e) {
    int c = threadIdx.x + e * 256;
    float xm = (v[e] - mean) * rstd * sg[c] + sb[c];
    float sc = eo[b * 1024 + c];
    float sh = eo[b * 1024 + D_ + c];
    float hm = xm * (1.f + sc) + sh;
    hs[row * D_ + c] = hm / (1.f + expf(-hm));
  }
}

extern "C" void kernel_launch(void* const* d_in, const int* in_sizes, int n_in,
                              void* d_out, int out_size, void* d_ws, size_t ws_size,
                              hipStream_t stream) {
  const float* x = (const float*)d_in[0];
  const float* xf = (const float*)d_in[1];
  const float* emb = (const float*)d_in[2];
  const float* norm_g = (const float*)d_in[3];
  const float* norm_b = (const float*)d_in[4];
  const float* tnorm_g = (const float*)d_in[5];
  const float* tnorm_b = (const float*)d_in[6];
  const float* Wq = (const float*)d_in[7];
  const float* bq = (const float*)d_in[8];
  const float* Wk = (const float*)d_in[9];
  const float* bk = (const float*)d_in[10];
  const float* Wv = (const float*)d_in[11];
  const float* bv = (const float*)d_in[12];
  const float* We = (const float*)d_in[13];
  const float* be = (const float*)d_in[14];
  const float* sg = (const float*)d_in[15];
  const float* sb = (const float*)d_in[16];
  const float* Wo = (const float*)d_in[17];
  const float* bo = (const float*)d_in[18];
  float* out = (float*)d_out;

  float* w = (float*)d_ws;
  float* bufA = w;                    // 33.5M floats: xn -> v -> hs
  float* bufB = bufA + 33554432;      // q
  float* bufC = bufB + 33554432;      // xfn -> attn/stats/embout
  float* bufD = bufC + 16777216;      // k -> y
  // total: 117,440,512 floats = 448 MiB

  float* attn = bufC;                  // 1,048,576 floats (after xfn dead)
  float* kmaxp = bufC + 1048576;       // 16384
  float* ksump = bufC + 1048576 + 16384;  // 16384
  float* embout = bufC + 1048576 + 32768; // 32768

  // 1. xn = LN(x)
  ln_rows<512><<<MROWS, 256, 0, stream>>>(x, norm_g, norm_b, bufA);
  // 2. q = xn @ Wq + bq
  gemm64<512, false><<<dim3(8, 1024), 256, 0, stream>>>(bufA, Wq, bq, nullptr, bufB, 512);
  // 3. xfn = LN(xf)
  ln_rows<256><<<MROWS, 256, 0, stream>>>(xf, tnorm_g, tnorm_b, bufC);
  // 4. k = xfn @ Wk + bk
  gemm64<256, false><<<dim3(8, 1024), 256, 0, stream>>>(bufC, Wk, bk, nullptr, bufD, 512);
  // 5. v = xfn @ Wv + bv   (bufA: xn is dead)
  gemm64<256, false><<<dim3(8, 1024), 256, 0, stream>>>(bufC, Wv, bv, nullptr, bufA, 512);
  // 6. k softmax stats (xfn dead from here; bufC reused)
  kstats<<<dim3(32, 8), 256, 0, stream>>>(bufD, kmaxp, ksump);
  // 7. attn = softmax(k)^T @ v
  hipMemsetAsync(attn, 0, (size_t)1048576 * 4, stream);
  attn_kernel<<<dim3(32, 8, 8), 256, 0, stream>>>(bufD, bufA, kmaxp, ksump, attn);
  // 8. emb modulation
  embmod<<<32, 256, 0, stream>>>(emb, We, be, embout);
  // 9. q softmax (in place)
  qsoftmax<<<131072, 256, 0, stream>>>(bufB);
  // 10. y = q @ attn  (bufD: k is dead)
  yein<<<dim3(64, 8, 32), 256, 0, stream>>>(bufB, attn, bufD);
  // 11. hs = silu(LN(y)*(1+scale)+shift)  (bufA: v is dead)
  modln<<<MROWS, 256, 0, stream>>>(bufD, sg, sb, embout, bufA);
  // 12. out = hs @ Wo + bo + x
  gemm64<512, true><<<dim3(8, 1024), 256, 0, stream>>>(bufA, Wo, bo, x, out, 512);
}

// Round 2
// 1361.492 us; speedup vs baseline: 1.8182x; 1.8182x over previous
//
#include <hip/hip_runtime.h>
#include <math.h>

#define B_ 32
#define T_ 2048
#define N_ 2048
#define D_ 512
#define L_ 256
#define TE_ 1024
#define H_ 8
#define MROWS 65536  // B*T = B*N

typedef __attribute__((ext_vector_type(8))) short short8;
typedef __attribute__((ext_vector_type(4))) float f32x4;

__device__ __forceinline__ unsigned short f2bf(float f) {
  unsigned u = __float_as_uint(f);
  unsigned r = (u + 0x7FFF + ((u >> 16) & 1)) >> 16;  // RNE
  return (unsigned short)r;
}
__device__ __forceinline__ float bf2f(unsigned short u) {
  return __uint_as_float(((unsigned)u) << 16);
}
__device__ __forceinline__ void gload_lds16(const void* g, void* l) {
  __builtin_amdgcn_global_load_lds(
      (const __attribute__((address_space(1))) void*)g,
      (__attribute__((address_space(3))) void*)l, 16, 0, 0);
}

// ---------------- block reduce (256 threads) ----------------
__device__ __forceinline__ float blockReduceSum(float v, float* ws) {
#pragma unroll
  for (int m = 32; m >= 1; m >>= 1) v += __shfl_xor(v, m, 64);
  int wid = threadIdx.x >> 6;
  int lane = threadIdx.x & 63;
  __syncthreads();
  if (lane == 0) ws[wid] = v;
  __syncthreads();
  return ws[0] + ws[1] + ws[2] + ws[3];
}

// ---------------- row LayerNorm -> bf16 ----------------
template <int COLS>
__global__ void __launch_bounds__(256) ln_rows(const float* __restrict__ in,
                                               const float* __restrict__ g,
                                               const float* __restrict__ bb,
                                               unsigned short* __restrict__ out) {
  constexpr int E = COLS / 256;
  __shared__ float ws[4];
  size_t row = blockIdx.x;
  const float* rp = in + row * COLS;
  float v[E];
  float s = 0.f;
#pragma unroll
  for (int e = 0; e < E; ++e) {
    v[e] = rp[threadIdx.x + e * 256];
    s += v[e];
  }
  s = blockReduceSum(s, ws);
  float mean = s * (1.0f / COLS);
  float q = 0.f;
#pragma unroll
  for (int e = 0; e < E; ++e) {
    float d = v[e] - mean;
    q += d * d;
  }
  q = blockReduceSum(q, ws);
  float rstd = rsqrtf(q * (1.0f / COLS) + 1e-5f);
  unsigned short* op = out + row * COLS;
#pragma unroll
  for (int e = 0; e < E; ++e) {
    int c = threadIdx.x + e * 256;
    op[c] = f2bf((v[e] - mean) * rstd * g[c] + bb[c]);
  }
}

// ---------------- weight transpose + cast: Wt[n][k] = bf16(W[k][n]) ----------------
__global__ void __launch_bounds__(256) transcast(const float* __restrict__ W,
                                                 unsigned short* __restrict__ Wt,
                                                 int K, int Ncols) {
  __shared__ float t[32][33];
  int k0 = blockIdx.x * 32, n0 = blockIdx.y * 32;
  int tx = threadIdx.x & 31, ty = threadIdx.x >> 5;  // 32 x 8
#pragma unroll
  for (int i = 0; i < 32; i += 8)
    t[ty + i][tx] = W[(size_t)(k0 + ty + i) * Ncols + n0 + tx];
  __syncthreads();
#pragma unroll
  for (int i = 0; i < 32; i += 8)
    Wt[(size_t)(n0 + ty + i) * K + k0 + tx] = f2bf(t[tx][ty + i]);
}

// ---------------- bf16 MFMA GEMM: C[M,512] = A[M,KT] @ Wt[512,KT]^T + bias (+add) ----------------
// 128x128 tile, 4 waves in 2x2, each wave 64x64 as 4x4 of 16x16x32 MFMA.
template <int KT, bool ADD, bool OUTBF>
__global__ void __launch_bounds__(256) gemm_mfma(const unsigned short* __restrict__ A,
                                                 const unsigned short* __restrict__ Wt,
                                                 const float* __restrict__ bias,
                                                 const float* __restrict__ add,
                                                 void* __restrict__ Cv) {
  __shared__ __align__(16) unsigned short sA[128 * 32];
  __shared__ __align__(16) unsigned short sB[128 * 32];
  int tid = threadIdx.x;
  int w = tid >> 6, lane = tid & 63;
  int quad = lane >> 4, r16 = lane & 15;
  int wr = w >> 1, wc = w & 1;
  size_t m0 = (size_t)blockIdx.y * 128;
  int n0 = blockIdx.x * 128;
  int srow = lane >> 2;        // 0..15
  int scol = (lane & 3) * 8;   // ushort offset within 32-wide K slice
  f32x4 acc[4][4] = {};

  for (int k0 = 0; k0 < KT; k0 += 32) {
    __syncthreads();  // previous compute must finish before LDS overwrite
#pragma unroll
    for (int i = 0; i < 2; ++i) {
      int seg = w * 2 + i;  // 0..7, 16 rows each
      gload_lds16(&A[(m0 + seg * 16 + srow) * KT + k0 + scol], &sA[seg * 512]);
    }
#pragma unroll
    for (int i = 0; i < 2; ++i) {
      int seg = w * 2 + i;
      gload_lds16(&Wt[(size_t)(n0 + seg * 16 + srow) * KT + k0 + scol], &sB[seg * 512]);
    }
    __syncthreads();  // compiler drains vmcnt here (global_load_lds done)
    short8 af[4], bfr[4];
#pragma unroll
    for (int mi = 0; mi < 4; ++mi)
      af[mi] = *(const short8*)&sA[(wr * 64 + mi * 16 + r16) * 32 + quad * 8];
#pragma unroll
    for (int ni = 0; ni < 4; ++ni)
      bfr[ni] = *(const short8*)&sB[(wc * 64 + ni * 16 + r16) * 32 + quad * 8];
#pragma unroll
    for (int mi = 0; mi < 4; ++mi)
#pragma unroll
      for (int ni = 0; ni < 4; ++ni)
        acc[mi][ni] = __builtin_amdgcn_mfma_f32_16x16x32_bf16(af[mi], bfr[ni], acc[mi][ni], 0, 0, 0);
  }

  float* Cf = (float*)Cv;
  unsigned short* Cb = (unsigned short*)Cv;
#pragma unroll
  for (int mi = 0; mi < 4; ++mi)
#pragma unroll
    for (int r = 0; r < 4; ++r) {
      size_t grow = m0 + wr * 64 + mi * 16 + quad * 4 + r;
#pragma unroll
      for (int ni = 0; ni < 4; ++ni) {
        int gcol = n0 + wc * 64 + ni * 16 + r16;
        float val = acc[mi][ni][r] + bias[gcol];
        if constexpr (ADD) val += add[grow * 512 + gcol];
        if constexpr (OUTBF)
          Cb[grow * 512 + gcol] = f2bf(val);
        else
          Cf[grow * 512 + gcol] = val;
      }
    }
}

// ---------------- softmax over contiguous 64-groups (q, bf16 in/out) ----------------
__global__ void __launch_bounds__(256) qsoftmax(unsigned short* __restrict__ q) {
  size_t w = (size_t)blockIdx.x * 4 + (threadIdx.x >> 6);
  int lane = threadIdx.x & 63;
  size_t idx = w * 64 + lane;
  float v = bf2f(q[idx]);
  float m = v;
#pragma unroll
  for (int s = 32; s >= 1; s >>= 1) m = fmaxf(m, __shfl_xor(m, s, 64));
  float e = expf(v - m);
  float ssum = e;
#pragma unroll
  for (int s = 32; s >= 1; s >>= 1) ssum += __shfl_xor(ssum, s, 64);
  q[idx] = f2bf(e / ssum);
}

// ---------------- k softmax stats over n (per b, channel) ----------------
__global__ void __launch_bounds__(256) kstats(const float* __restrict__ k,
                                              float* __restrict__ kmax,
                                              float* __restrict__ ksum) {
  int b = blockIdx.x, cg = blockIdx.y;
  int tid = threadIdx.x;
  int lane = tid & 63, slice = tid >> 6;
  int c = cg * 64 + lane;
  const float* kp = k + (size_t)b * N_ * D_ + c;
  float m = -1e30f;
  for (int n = slice; n < N_; n += 4) m = fmaxf(m, kp[(size_t)n * D_]);
  __shared__ float red[256];
  __shared__ float mxs[64];
  red[tid] = m;
  __syncthreads();
  if (tid < 64)
    mxs[tid] = fmaxf(fmaxf(red[tid], red[tid + 64]), fmaxf(red[tid + 128], red[tid + 192]));
  __syncthreads();
  float mm = mxs[lane];
  float s = 0.f;
  for (int n = slice; n < N_; n += 4) s += expf(kp[(size_t)n * D_] - mm);
  __syncthreads();
  red[tid] = s;
  __syncthreads();
  if (tid < 64) {
    float ss = red[tid] + red[tid + 64] + red[tid + 128] + red[tid + 192];
    kmax[b * D_ + cg * 64 + tid] = mxs[tid];
    ksum[b * D_ + cg * 64 + tid] = ss;
  }
}

// ---------------- attn[b,h] += Kx^T @ V over an n-chunk of 256 ----------------
__global__ void __launch_bounds__(256) attn_kernel(const float* __restrict__ k,
                                                   const float* __restrict__ v,
                                                   const float* __restrict__ kmax,
                                                   const float* __restrict__ ksum,
                                                   float* __restrict__ attn) {
  int b = blockIdx.x, h = blockIdx.y, nc = blockIdx.z;
  int tid = threadIdx.x;
  __shared__ float ks_[32][68];
  __shared__ float vs_[32][68];
  __shared__ float mx[64], is_[64];
  if (tid < 64) {
    mx[tid] = kmax[b * D_ + h * 64 + tid];
    is_[tid] = 1.f / ksum[b * D_ + h * 64 + tid];
  }
  const float* kp = k + ((size_t)b * N_ + nc * 256) * D_ + h * 64;
  const float* vp = v + ((size_t)b * N_ + nc * 256) * D_ + h * 64;
  float acc[4][4] = {};
  int tx = tid & 15, ty = tid >> 4;
  int lr = tid >> 4;
  int c4 = (tid & 15) * 4;
  for (int n0 = 0; n0 < 256; n0 += 32) {
    __syncthreads();
#pragma unroll
    for (int rr = 0; rr < 32; rr += 16) {
      float4 kv = *(const float4*)&kp[(size_t)(n0 + lr + rr) * D_ + c4];
      float4 vv = *(const float4*)&vp[(size_t)(n0 + lr + rr) * D_ + c4];
      ks_[lr + rr][c4 + 0] = expf(kv.x - mx[c4 + 0]) * is_[c4 + 0];
      ks_[lr + rr][c4 + 1] = expf(kv.y - mx[c4 + 1]) * is_[c4 + 1];
      ks_[lr + rr][c4 + 2] = expf(kv.z - mx[c4 + 2]) * is_[c4 + 2];
      ks_[lr + rr][c4 + 3] = expf(kv.w - mx[c4 + 3]) * is_[c4 + 3];
      vs_[lr + rr][c4 + 0] = vv.x;
      vs_[lr + rr][c4 + 1] = vv.y;
      vs_[lr + rr][c4 + 2] = vv.z;
      vs_[lr + rr][c4 + 3] = vv.w;
    }
    __syncthreads();
#pragma unroll
    for (int nn = 0; nn < 32; ++nn) {
      float av[4], bv2[4];
#pragma unroll
      for (int i = 0; i < 4; ++i) av[i] = ks_[nn][ty * 4 + i];
#pragma unroll
      for (int j = 0; j < 4; ++j) bv2[j] = vs_[nn][tx * 4 + j];
#pragma unroll
      for (int i = 0; i < 4; ++i)
#pragma unroll
        for (int j = 0; j < 4; ++j) acc[i][j] += av[i] * bv2[j];
    }
  }
  float* ap = attn + (size_t)(b * H_ + h) * 4096;
#pragma unroll
  for (int i = 0; i < 4; ++i)
#pragma unroll
    for (int j = 0; j < 4; ++j)
      atomicAdd(&ap[(ty * 4 + i) * 64 + tx * 4 + j], acc[i][j]);
}

// ---------------- emb modulation: eo = silu(emb) @ We + be ----------------
__global__ void __launch_bounds__(256) embmod(const float* __restrict__ emb,
                                              const float* __restrict__ We,
                                              const float* __restrict__ be,
                                              float* __restrict__ eo) {
  int b = blockIdx.x, tid = threadIdx.x;
  __shared__ float se[TE_];
  for (int i = tid; i < TE_; i += 256) {
    float e = emb[b * TE_ + i];
    se[i] = e / (1.f + expf(-e));
  }
  __syncthreads();
  int j0 = tid * 4;
  float a0 = 0, a1 = 0, a2 = 0, a3 = 0;
  for (int i = 0; i < TE_; ++i) {
    float s = se[i];
    float4 wv = *(const float4*)&We[(size_t)i * 1024 + j0];
    a0 += s * wv.x;
    a1 += s * wv.y;
    a2 += s * wv.z;
    a3 += s * wv.w;
  }
  eo[b * 1024 + j0 + 0] = a0 + be[j0 + 0];
  eo[b * 1024 + j0 + 1] = a1 + be[j0 + 1];
  eo[b * 1024 + j0 + 2] = a2 + be[j0 + 2];
  eo[b * 1024 + j0 + 3] = a3 + be[j0 + 3];
}

// ---------------- y[b,t,h,:] = q[b,t,h,:] @ attn[b,h]  (q is bf16) ----------------
__global__ void __launch_bounds__(256) yein(const unsigned short* __restrict__ q,
                                            const float* __restrict__ attn,
                                            float* __restrict__ y) {
  int t0 = blockIdx.x * 32, h = blockIdx.y, b = blockIdx.z;
  int tid = threadIdx.x;
  __shared__ float at[64][68];
  __shared__ float qs[32][68];
  const float* ap = attn + (size_t)(b * H_ + h) * 4096;
  for (int i = tid; i < 4096; i += 256) at[i >> 6][i & 63] = ap[i];
  const unsigned short* qp = q + ((size_t)b * T_ + t0) * D_ + h * 64;
  for (int i = tid; i < 2048; i += 256)
    qs[i >> 6][i & 63] = bf2f(qp[(size_t)(i >> 6) * D_ + (i & 63)]);
  __syncthreads();
  int r = tid >> 3, c0 = (tid & 7) * 8;
  float acc[8] = {};
#pragma unroll
  for (int d = 0; d < 64; ++d) {
    float qv = qs[r][d];
#pragma unroll
    for (int j = 0; j < 8; ++j) acc[j] += qv * at[d][c0 + j];
  }
  float* yp = y + ((size_t)b * T_ + t0 + r) * D_ + h * 64 + c0;
#pragma unroll
  for (int j = 0; j < 8; ++j) yp[j] = acc[j];
}

// ---------------- LN(y) * (1+scale) + shift, then silu -> bf16 ----------------
__global__ void __launch_bounds__(256) modln(const float* __restrict__ y,
                                             const float* __restrict__ sg,
                                             const float* __restrict__ sb,
                                             const float* __restrict__ eo,
                                             unsigned short* __restrict__ hs) {
  __shared__ float ws[4];
  size_t row = blockIdx.x;
  int b = (int)(row >> 11);
  const float* rp = y + row * D_;
  float v[2];
  float s = 0.f;
#pragma unroll
  for (int e = 0; e < 2; ++e) {
    v[e] = rp[threadIdx.x + e * 256];
    s += v[e];
  }
  s = blockReduceSum(s, ws);
  float mean = s * (1.0f / D_);
  float q = 0.f;
#pragma unroll
  for (int e = 0; e < 2; ++e) {
    float d = v[e] - mean;
    q += d * d;
  }
  q = blockReduceSum(q, ws);
  float rstd = rsqrtf(q * (1.0f / D_) + 1e-5f);
#pragma unroll
  for (int e = 0; e < 2; ++e) {
    int c = threadIdx.x + e * 256;
    float xm = (v[e] - mean) * rstd * sg[c] + sb[c];
    float sc = eo[b * 1024 + c];
    float sh = eo[b * 1024 + D_ + c];
    float hm = xm * (1.f + sc) + sh;
    hs[row * D_ + c] = f2bf(hm / (1.f + expf(-hm)));
  }
}

extern "C" void kernel_launch(void* const* d_in, const int* in_sizes, int n_in,
                              void* d_out, int out_size, void* d_ws, size_t ws_size,
                              hipStream_t stream) {
  const float* x = (const float*)d_in[0];
  const float* xf = (const float*)d_in[1];
  const float* emb = (const float*)d_in[2];
  const float* norm_g = (const float*)d_in[3];
  const float* norm_b = (const float*)d_in[4];
  const float* tnorm_g = (const float*)d_in[5];
  const float* tnorm_b = (const float*)d_in[6];
  const float* Wq = (const float*)d_in[7];
  const float* bq = (const float*)d_in[8];
  const float* Wk = (const float*)d_in[9];
  const float* bk = (const float*)d_in[10];
  const float* Wv = (const float*)d_in[11];
  const float* bv = (const float*)d_in[12];
  const float* We = (const float*)d_in[13];
  const float* be = (const float*)d_in[14];
  const float* sg = (const float*)d_in[15];
  const float* sb = (const float*)d_in[16];
  const float* Wo = (const float*)d_in[17];
  const float* bo = (const float*)d_in[18];
  float* out = (float*)d_out;

  float* w = (float*)d_ws;
  // layout (floats):
  unsigned short* qbf = (unsigned short*)w;               // 33.5M ushort = 16.78M floats
  float* kbuf = w + 16777216;                             // 33.5M floats (k -> y)
  float* vbuf = w + 16777216 + 33554432;                  // 33.5M floats
  unsigned short* xnbf = (unsigned short*)(w + 83886080); // 33.5M ushort (xn -> hs)
  unsigned short* xfnbf = (unsigned short*)(w + 100663296); // 16.78M ushort
  float* attn = w + 109051904;                            // 1,048,576
  float* kmaxp = attn + 1048576;                          // 16384
  float* ksump = kmaxp + 16384;                           // 16384
  float* embout = ksump + 16384;                          // 32768
  unsigned short* wqt = (unsigned short*)(embout + 32768);  // 512*512
  unsigned short* wkt = wqt + 262144;                       // 512*256
  unsigned short* wvt = wkt + 131072;                       // 512*256
  unsigned short* wot = wvt + 131072;                       // 512*512
  // total ~110.6M floats = 442 MiB

  // 0. weight transpose-casts (tiny)
  transcast<<<dim3(16, 16), 256, 0, stream>>>(Wq, wqt, 512, 512);
  transcast<<<dim3(8, 16), 256, 0, stream>>>(Wk, wkt, 256, 512);
  transcast<<<dim3(8, 16), 256, 0, stream>>>(Wv, wvt, 256, 512);
  transcast<<<dim3(16, 16), 256, 0, stream>>>(Wo, wot, 512, 512);
  // 1. xn = LN(x) -> bf16
  ln_rows<512><<<MROWS, 256, 0, stream>>>(x, norm_g, norm_b, xnbf);
  // 2. q = xn @ Wq + bq -> bf16
  gemm_mfma<512, false, true><<<dim3(4, 512), 256, 0, stream>>>(xnbf, wqt, bq, nullptr, qbf);
  // 3. xfn = LN(xf) -> bf16
  ln_rows<256><<<MROWS, 256, 0, stream>>>(xf, tnorm_g, tnorm_b, xfnbf);
  // 4. k = xfn @ Wk + bk -> fp32
  gemm_mfma<256, false, false><<<dim3(4, 512), 256, 0, stream>>>(xfnbf, wkt, bk, nullptr, kbuf);
  // 5. v = xfn @ Wv + bv -> fp32
  gemm_mfma<256, false, false><<<dim3(4, 512), 256, 0, stream>>>(xfnbf, wvt, bv, nullptr, vbuf);
  // 6. k softmax stats
  kstats<<<dim3(32, 8), 256, 0, stream>>>(kbuf, kmaxp, ksump);
  // 7. attn = softmax(k)^T @ v
  hipMemsetAsync(attn, 0, (size_t)1048576 * 4, stream);
  attn_kernel<<<dim3(32, 8, 8), 256, 0, stream>>>(kbuf, vbuf, kmaxp, ksump, attn);
  // 8. emb modulation
  embmod<<<32, 256, 0, stream>>>(emb, We, be, embout);
  // 9. q softmax (in place, bf16)
  qsoftmax<<<131072, 256, 0, stream>>>(qbf);
  // 10. y = q @ attn -> kbuf (k dead)
  yein<<<dim3(64, 8, 32), 256, 0, stream>>>(qbf, attn, kbuf);
  // 11. hs = silu(LN(y)*(1+scale)+shift) -> bf16 into xnbf (xn dead)
  modln<<<MROWS, 256, 0, stream>>>(kbuf, sg, sb, embout, xnbf);
  // 12. out = hs @ Wo + bo + x
  gemm_mfma<512, true, false><<<dim3(4, 512), 256, 0, stream>>>(xnbf, wot, bo, x, out);
}